// Round 7
// baseline (1042.476 us; speedup 1.0000x reference)
//
#include <hip/hip_runtime.h>

// ---------------------------------------------------------------------------
// R7: reproduce the reference AS WRITTEN. The jax reference's second _rnn call
// receives y1 in [B,T,H] layout, so lax.scan runs over the BATCH axis; with
// last = y2[:,-1,:] the net computation is:
//   (1) per-seq layer-1 RNN over time, keep final h1[b] only   (parallel)
//   (2) one chain over b: h2_b = tanh(Wih2 h1[b] + b2 + Whh2 h2_{b-1})  (serial)
//   (3) out[b] = Wfc h2_b + bfc                                 (parallel)
// All prior rounds implemented layer-2-over-time -> stable 0.5068 absmax.
// Dtypes: fp32 in / fp32 out (R6's bf16 reinterpretation NaN'd -> fp32 proven).
// K1 uses the R4 16-lane xor-swizzle gather (bit-identical to scalar R5).
// ---------------------------------------------------------------------------

constexpr int QP0 = 0x00, QP1 = 0x55, QP2 = 0xAA;  // quad_perm bcast lane c

template <int CTRL>
__device__ __forceinline__ float dppf(float v) {
    return __int_as_float(__builtin_amdgcn_update_dpp(
        0, __float_as_int(v), CTRL, 0xF, 0xF, true));
}
// XOR lane swizzle: lane i reads lane i^XORM (BitMode, and=0x1F).
template <int XORM>
__device__ __forceinline__ float swzf(float v) {
    constexpr int OFF = (XORM << 10) | 0x1F;
    return __int_as_float(__builtin_amdgcn_ds_swizzle(__float_as_int(v), OFF));
}

// tanh = 1 - 2/(2^(2x*log2e)+1); hw exp2 + rcp, rel err ~2e-7, inf-safe.
__device__ __forceinline__ float tanh_fast(float a) {
    float t = a * 2.8853900817779268f;
    float e = __builtin_amdgcn_exp2f(t);
    float r = __builtin_amdgcn_rcpf(e + 1.0f);
    return fmaf(-2.0f, r, 1.0f);
}

__device__ __forceinline__ int qbase(int s) { return 3 * s - ((s > 2) ? (s - 2) : 0); }

// acc += W.h where h is distributed over the 16-lane group (quad m holds rows
// qbase(m)..; lane c<cnt(m) of quad m owns row qbase(m)+c). Hop k = xor 4k.
__device__ __forceinline__ float gmv(float P, const float* w, float acc) {
    float g1 = swzf<4>(P);
    float g2 = swzf<8>(P);
    float g3 = swzf<12>(P);
    float a0 = fmaf(dppf<QP0>(P),  w[0],  acc);
    float a1 = dppf<QP1>(P) * w[1];
    a0 = fmaf(dppf<QP2>(P),  w[2],  a0);
    a1 = fmaf(dppf<QP0>(g1), w[3],  a1);
    a0 = fmaf(dppf<QP1>(g1), w[4],  a0);
    a1 = fmaf(dppf<QP2>(g1), w[5],  a1);
    a0 = fmaf(dppf<QP0>(g2), w[6],  a0);
    a1 = fmaf(dppf<QP1>(g2), w[7],  a1);
    a0 = fmaf(dppf<QP2>(g2), w[8],  a0);
    a1 = fmaf(dppf<QP0>(g3), w[9],  a1);
    a0 = fmaf(dppf<QP1>(g3), w[10], a0);
    a1 = fmaf(dppf<QP2>(g3), w[11], a1);
    return a0 + a1;
}

// w[k*3+c] = M[row][qbase(q^k)+c] for valid slots, else 0.
__device__ __forceinline__ void load12(const float* __restrict__ M, int row,
                                       bool rv, int q, float* w) {
#pragma unroll
    for (int k = 0; k < 4; ++k) {
        int s = q ^ k;
        int bs = qbase(s);
        int cn = (s < 2) ? 3 : 2;
#pragma unroll
        for (int c = 0; c < 3; ++c)
            w[k * 3 + c] = (rv && c < cn) ? M[row * 10 + bs + c] : 0.0f;
    }
}

// ---- K1: layer-1 scan per sequence; writes pre[b] = Wih2.h1_final + b2 -----
__global__ __launch_bounds__(256) void k1_layer1(
    const float* __restrict__ x,
    const float* __restrict__ Wih1, const float* __restrict__ Whh1,
    const float* __restrict__ bih1, const float* __restrict__ bhh1,
    const float* __restrict__ Wih2,
    const float* __restrict__ bih2, const float* __restrict__ bhh2,
    float* __restrict__ pre, int B, int T)
{
    const int l16 = threadIdx.x & 15;
    int seq = blockIdx.x * 16 + (threadIdx.x >> 4);
    const bool seqv = (seq < B);
    if (!seqv) seq = B - 1;

    const int q  = l16 >> 2;
    const int cl = l16 & 3;
    const int myc = (q < 2) ? 3 : 2;
    const bool rv = (cl < myc);
    const int row = qbase(q) + cl;

    float wh1[12], wi2[12];
    load12(Whh1, row, rv, q, wh1);
    load12(Wih2, row, rv, q, wi2);

    const float wx0 = rv ? Wih1[row * 2 + 0] : 0.0f;
    const float wx1 = rv ? Wih1[row * 2 + 1] : 0.0f;
    const float b1  = rv ? (bih1[row] + bhh1[row]) : 0.0f;
    const float b2  = rv ? (bih2[row] + bhh2[row]) : 0.0f;

    const float2* xp = (const float2*)(x + (size_t)seq * (size_t)T * 2);
    float2 xc = xp[0];
    float P1 = 0.0f;

    for (int t = 0; t < T; ++t) {
        int tn = (t + 1 < T) ? (t + 1) : t;
        float2 xn = xp[tn];
        float a1 = fmaf(wx1, xc.y, fmaf(wx0, xc.x, b1));
        a1 = gmv(P1, wh1, a1);
        P1 = tanh_fast(a1);
        xc = xn;
    }

    float pv = gmv(P1, wi2, b2);         // Wih2 . h1_final + (bih2+bhh2)
    if (seqv && rv) pre[(size_t)seq * 10 + row] = pv;
}

// ---- K2: serial chain over b (single wave does the work) -------------------
__global__ __launch_bounds__(64) void k2_chain(
    const float* __restrict__ Whh2,
    const float* __restrict__ pre,       // [B][10]
    float* __restrict__ h2s,             // [B][10] out
    int B)
{
    const int l16 = threadIdx.x & 15;
    const int q  = l16 >> 2;
    const int cl = l16 & 3;
    const int myc = (q < 2) ? 3 : 2;
    const bool rv = (cl < myc);
    const int row = qbase(q) + cl;
    const int prow = rv ? row : 0;       // safe address for idle lanes

    float wh2[12];
    load12(Whh2, row, rv, q, wh2);

    const bool st = (threadIdx.x < 16) && rv;   // only wave-front 16 stores

    // prefetch ring, depth 4
    float pf[4];
#pragma unroll
    for (int i = 0; i < 4; ++i) {
        int bb = (i < B) ? i : (B - 1);
        pf[i] = pre[(size_t)bb * 10 + prow];
    }

    float P2 = 0.0f;
    for (int b = 0; b < B; b += 4) {
#pragma unroll
        for (int u = 0; u < 4; ++u) {
            float prv = pf[u];
            int bn = b + u + 4; if (bn >= B) bn = B - 1;
            pf[u] = pre[(size_t)bn * 10 + prow];      // off-chain prefetch
            float a = gmv(P2, wh2, prv);
            P2 = tanh_fast(a);
            if (st) h2s[(size_t)(b + u) * 10 + row] = P2;
        }
    }
}

// ---- K3: FC over all b (parallel) ------------------------------------------
__global__ __launch_bounds__(256) void k3_fc(
    const float* __restrict__ h2s, const float* __restrict__ Wfc,
    const float* __restrict__ bfc, float* __restrict__ out, int N)
{
    int i = blockIdx.x * 256 + threadIdx.x;
    if (i >= N) return;
    int b = i >> 2, j = i & 3;
    float a = bfc[j];
#pragma unroll
    for (int k = 0; k < 10; ++k)
        a = fmaf(Wfc[j * 10 + k], h2s[(size_t)b * 10 + k], a);
    out[i] = a;
}

extern "C" void kernel_launch(void* const* d_in, const int* in_sizes, int n_in,
                              void* d_out, int out_size, void* d_ws, size_t ws_size,
                              hipStream_t stream) {
    const float* x    = (const float*)d_in[0];
    const float* Wih1 = (const float*)d_in[1];
    const float* Whh1 = (const float*)d_in[2];
    const float* bih1 = (const float*)d_in[3];
    const float* bhh1 = (const float*)d_in[4];
    const float* Wih2 = (const float*)d_in[5];
    const float* Whh2 = (const float*)d_in[6];
    const float* bih2 = (const float*)d_in[7];
    const float* bhh2 = (const float*)d_in[8];
    const float* Wfc  = (const float*)d_in[9];
    const float* bfc  = (const float*)d_in[10];
    float* out = (float*)d_out;

    const int B = out_size / 4;                 // 4096
    const int T = in_sizes[0] / (2 * B);        // 2048

    float* ws_pre = (float*)d_ws;               // [B][10]
    float* ws_h2  = ws_pre + (size_t)B * 10;    // [B][10]

    hipLaunchKernelGGL(k1_layer1, dim3((B + 15) / 16), dim3(256), 0, stream,
                       x, Wih1, Whh1, bih1, bhh1, Wih2, bih2, bhh2,
                       ws_pre, B, T);
    hipLaunchKernelGGL(k2_chain, dim3(1), dim3(64), 0, stream,
                       Whh2, ws_pre, ws_h2, B);
    hipLaunchKernelGGL(k3_fc, dim3((B * 4 + 255) / 256), dim3(256), 0, stream,
                       ws_h2, Wfc, bfc, out, B * 4);
}

// Round 8
// 777.125 us; speedup vs baseline: 1.3415x; 1.3415x over previous
//
#include <hip/hip_runtime.h>

// ---------------------------------------------------------------------------
// R8: latency attack. Algorithm (validated in R7): layer-1 RNN over time per
// sequence (parallel), then ONE serial chain over the batch axis for layer 2
// (the reference's lax.scan runs over axis 0 of a [B,T,H] array = batch),
// then parallel FC on h2.
// R7 -> R8:
//  * ds_swizzle (LDS crossbar, ~120 cy on the serial chain) -> DPP row_ror
//    hops (~5 cy, VALU pipe). ROR gather + self-calibration was proven
//    numerically equivalent to the xor-swizzle and scalar gathers in R1/R4/R5.
//  * recurrent weights pre-scaled by 2*log2(e): kills the tanh input multiply
//    on the chain (k1 writes `pre` pre-scaled for k2).
//  * FMA tree: 4 chains of 3 + binary merge (latency ~20 cy vs 28).
//  * k1: float4 x-loads (2 steps/load), 2-deep ring, 2-step unroll.
//  * k2: 8-step unroll, 8-deep prefetch ring (~400 cy load cover).
// ---------------------------------------------------------------------------

constexpr int ROR4 = 0x124, ROR8 = 0x128, ROR12 = 0x12C;   // row_ror:4/8/12
constexpr int QP0 = 0x00, QP1 = 0x55, QP2 = 0xAA;          // quad_perm bcast
constexpr float SCL = 2.8853900817779268f;                  // 2*log2(e)

template <int CTRL>
__device__ __forceinline__ float dppf(float v) {
    return __int_as_float(__builtin_amdgcn_update_dpp(
        0, __float_as_int(v), CTRL, 0xF, 0xF, true));
}
template <int CTRL>
__device__ __forceinline__ int dppi(int v) {
    return __builtin_amdgcn_update_dpp(0, v, CTRL, 0xF, 0xF, true);
}

// tanh from PRE-SCALED input z = x*2log2e:  tanh = 1 - 2/(2^z + 1).
__device__ __forceinline__ float tanh_scaled(float z) {
    float e = __builtin_amdgcn_exp2f(z);
    float r = __builtin_amdgcn_rcpf(e + 1.0f);
    return fmaf(-2.0f, r, 1.0f);
}

__device__ __forceinline__ int qbase(int s) { return 3 * s - ((s > 2) ? (s - 2) : 0); }

// acc += W.h, h distributed over the 16-lane group (quad m: rows qbase(m)..,
// lane c<cnt(m) owns row qbase(m)+c). Inter-quad: DPP row_ror; intra-quad:
// quad_perm broadcast (single-use -> folds into the FMA). 4 chains of 3.
__device__ __forceinline__ float gmv(float P, const float* w, float acc) {
    float g1 = dppf<ROR4>(P);
    float g2 = dppf<ROR8>(P);
    float g3 = dppf<ROR12>(P);
    float a0 = fmaf(dppf<QP0>(P),  w[0],  acc);
    float a1 =      dppf<QP0>(g1) * w[3];
    float a2 =      dppf<QP0>(g2) * w[6];
    float a3 =      dppf<QP0>(g3) * w[9];
    a0 = fmaf(dppf<QP1>(P),  w[1],  a0);
    a1 = fmaf(dppf<QP1>(g1), w[4],  a1);
    a2 = fmaf(dppf<QP1>(g2), w[7],  a2);
    a3 = fmaf(dppf<QP1>(g3), w[10], a3);
    a0 = fmaf(dppf<QP2>(P),  w[2],  a0);
    a1 = fmaf(dppf<QP2>(g1), w[5],  a1);
    a2 = fmaf(dppf<QP2>(g2), w[8],  a2);
    a3 = fmaf(dppf<QP2>(g3), w[11], a3);
    return (a0 + a1) + (a2 + a3);
}

// w[k*3+c] = scale * M[row][qbase(sk[k])+c] for valid slots, else 0.
__device__ __forceinline__ void load12(const float* __restrict__ M, int row,
                                       bool rv, const int* sk, float scale,
                                       float* w) {
#pragma unroll
    for (int k = 0; k < 4; ++k) {
        int s = sk[k];
        int bs = qbase(s);
        int cn = (s < 2) ? 3 : 2;
#pragma unroll
        for (int c = 0; c < 3; ++c)
            w[k * 3 + c] = (rv && c < cn) ? scale * M[row * 10 + bs + c] : 0.0f;
    }
}

// ---- K1: layer-1 scan per sequence; writes pre[b] = SCL*(Wih2.h1_T + b2) ---
__global__ __launch_bounds__(256) void k1_layer1(
    const float* __restrict__ x,
    const float* __restrict__ Wih1, const float* __restrict__ Whh1,
    const float* __restrict__ bih1, const float* __restrict__ bhh1,
    const float* __restrict__ Wih2,
    const float* __restrict__ bih2, const float* __restrict__ bhh2,
    float* __restrict__ pre, int B, int T)
{
    const int l16 = threadIdx.x & 15;
    int seq = blockIdx.x * 16 + (threadIdx.x >> 4);
    const bool seqv = (seq < B);
    if (!seqv) seq = B - 1;

    const int q  = l16 >> 2;
    const int cl = l16 & 3;
    const int myc = (q < 2) ? 3 : 2;
    const bool rv = (cl < myc);
    const int row = qbase(q) + cl;

    // self-calibrate which quad each ROR hop reaches (direction-agnostic)
    int sk[4];
    sk[0] = q;
    sk[1] = dppi<ROR4>(q);
    sk[2] = dppi<ROR8>(q);
    sk[3] = dppi<ROR12>(q);

    float wh1[12], wi2[12];
    load12(Whh1, row, rv, sk, SCL,  wh1);   // scaled: feeds tanh directly
    load12(Wih2, row, rv, sk, 1.0f, wi2);   // unscaled; epilogue scales

    const float wx0 = rv ? SCL * Wih1[row * 2 + 0] : 0.0f;
    const float wx1 = rv ? SCL * Wih1[row * 2 + 1] : 0.0f;
    const float b1  = rv ? SCL * (bih1[row] + bhh1[row]) : 0.0f;
    const float b2  = rv ? (bih2[row] + bhh2[row]) : 0.0f;

    // x as float4 = 2 timesteps per load; 2-deep ring (prefetch ~4 steps out)
    const float4* xp4 = (const float4*)(x + (size_t)seq * (size_t)T * 2);
    const int NI = T >> 1;                   // T even
    float4 r0 = xp4[0];
    float4 r1 = xp4[(1 < NI) ? 1 : (NI - 1)];
    float P1 = 0.0f;

    for (int i = 0; i < NI; ++i) {
        float4 cur = r0;
        r0 = r1;
        int nn = i + 2; if (nn >= NI) nn = NI - 1;
        r1 = xp4[nn];                        // off-chain prefetch

        // step 2i   (base terms independent of P1 -> scheduled early)
        float base0 = fmaf(wx1, cur.y, fmaf(wx0, cur.x, b1));
        float z0 = gmv(P1, wh1, base0);
        P1 = tanh_scaled(z0);
        // step 2i+1
        float base1 = fmaf(wx1, cur.w, fmaf(wx0, cur.z, b1));
        float z1 = gmv(P1, wh1, base1);
        P1 = tanh_scaled(z1);
    }

    float pv = SCL * gmv(P1, wi2, b2);       // pre-scaled for k2's chain
    if (seqv && rv) pre[(size_t)seq * 10 + row] = pv;
}

// ---- K2: serial chain over b; one wave. pre is PRE-SCALED by SCL. ----------
__global__ __launch_bounds__(64) void k2_chain(
    const float* __restrict__ Whh2,
    const float* __restrict__ pre,       // [B][10], scaled
    float* __restrict__ h2s,             // [B][10] out (unscaled tanh)
    int B)
{
    const int l16 = threadIdx.x & 15;
    const int q  = l16 >> 2;
    const int cl = l16 & 3;
    const int myc = (q < 2) ? 3 : 2;
    const bool rv = (cl < myc);
    const int row = qbase(q) + cl;
    const int prow = rv ? row : 0;

    int sk[4];
    sk[0] = q;
    sk[1] = dppi<ROR4>(q);
    sk[2] = dppi<ROR8>(q);
    sk[3] = dppi<ROR12>(q);

    float wh2[12];
    load12(Whh2, row, rv, sk, SCL, wh2);    // scaled: z feeds tanh directly

    const bool st = (threadIdx.x < 16) && rv;

    // 8-deep prefetch ring (~8 steps * ~55cy = covers L2/L3 latency)
    float pf[8];
#pragma unroll
    for (int i = 0; i < 8; ++i) {
        int bb = (i < B) ? i : (B - 1);
        pf[i] = pre[(size_t)bb * 10 + prow];
    }

    float P2 = 0.0f;
    for (int b = 0; b < B; b += 8) {
#pragma unroll
        for (int u = 0; u < 8; ++u) {
            float prv = pf[u];
            int bn = b + u + 8; if (bn >= B) bn = B - 1;
            pf[u] = pre[(size_t)bn * 10 + prow];     // off-chain
            float z = gmv(P2, wh2, prv);             // scaled pre-activation
            P2 = tanh_scaled(z);
            if (st && (b + u) < B) h2s[(size_t)(b + u) * 10 + row] = P2;
        }
    }
}

// ---- K3: FC over all b (parallel) ------------------------------------------
__global__ __launch_bounds__(256) void k3_fc(
    const float* __restrict__ h2s, const float* __restrict__ Wfc,
    const float* __restrict__ bfc, float* __restrict__ out, int N)
{
    int i = blockIdx.x * 256 + threadIdx.x;
    if (i >= N) return;
    int b = i >> 2, j = i & 3;
    float a = bfc[j];
#pragma unroll
    for (int k = 0; k < 10; ++k)
        a = fmaf(Wfc[j * 10 + k], h2s[(size_t)b * 10 + k], a);
    out[i] = a;
}

extern "C" void kernel_launch(void* const* d_in, const int* in_sizes, int n_in,
                              void* d_out, int out_size, void* d_ws, size_t ws_size,
                              hipStream_t stream) {
    const float* x    = (const float*)d_in[0];
    const float* Wih1 = (const float*)d_in[1];
    const float* Whh1 = (const float*)d_in[2];
    const float* bih1 = (const float*)d_in[3];
    const float* bhh1 = (const float*)d_in[4];
    const float* Wih2 = (const float*)d_in[5];
    const float* Whh2 = (const float*)d_in[6];
    const float* bih2 = (const float*)d_in[7];
    const float* bhh2 = (const float*)d_in[8];
    const float* Wfc  = (const float*)d_in[9];
    const float* bfc  = (const float*)d_in[10];
    float* out = (float*)d_out;

    const int B = out_size / 4;                 // 4096
    const int T = in_sizes[0] / (2 * B);        // 2048

    float* ws_pre = (float*)d_ws;               // [B][10] (scaled)
    float* ws_h2  = ws_pre + (size_t)B * 10;    // [B][10]

    hipLaunchKernelGGL(k1_layer1, dim3((B + 15) / 16), dim3(256), 0, stream,
                       x, Wih1, Whh1, bih1, bhh1, Wih2, bih2, bhh2,
                       ws_pre, B, T);
    hipLaunchKernelGGL(k2_chain, dim3(1), dim3(64), 0, stream,
                       Whh2, ws_pre, ws_h2, B);
    hipLaunchKernelGGL(k3_fc, dim3((B * 4 + 255) / 256), dim3(256), 0, stream,
                       ws_h2, Wfc, bfc, out, B * 4);
}